// Round 1
// 1438.975 us; speedup vs baseline: 1.2482x; 1.2482x over previous
//
#include <hip/hip_runtime.h>

// Grouped GEMM: out[g*2048+b][n] = sum_k x[g*2048+b][k] * w[g][k][n]
// G=8, M_per_g=2048, K=4096, N=4096, fp32 in/out, bf16 MFMA compute.
//
// Fast path (needs 402.7 MB workspace):
//   cvt_x:   x fp32 -> bf16 [16384][4096]
//   cvt_wT:  w fp32 [g][k][n] -> bf16 [g][n][k]
//   gemm_bt256: 256x256 tile, BK=64, 8 waves, 8-phase counted-vmcnt schedule
//               (T1 XCD swizzle + T2 LDS XOR swizzle + T3/T4 counted vmcnt
//                + T5 setprio), global_load_lds(16B) staging.
// Fallback (no workspace): fused-conversion 128^2 GEMM.

#define K_DIM 4096
#define N_DIM 4096
#define M_TOT 16384
#define GROUPS 8

typedef __bf16 bf16x8 __attribute__((ext_vector_type(8)));
typedef float f32x4 __attribute__((ext_vector_type(4)));

__device__ __forceinline__ unsigned short f2bf(float f) {
  // round-to-nearest-even fp32 -> bf16 (inputs are finite normals)
  unsigned int u = __builtin_bit_cast(unsigned int, f);
  return (unsigned short)((u + 0x7FFFu + ((u >> 16) & 1u)) >> 16);
}

#define GLOAD_LDS16(gp, lp)                                          \
  __builtin_amdgcn_global_load_lds(                                  \
      (__attribute__((address_space(1))) void*)(void*)(gp),          \
      (__attribute__((address_space(3))) void*)(void*)(lp), 16, 0, 0)

// ---------------------------------------------------------------------------
// Phase 1a: x fp32 -> bf16, 8 elements/thread, 16B stores
__global__ __launch_bounds__(256) void cvt_x_kernel(const float* __restrict__ x,
                                                    unsigned short* __restrict__ xb) {
  size_t i = (size_t)blockIdx.x * 256 + threadIdx.x;  // handles floats [8i, 8i+8)
  const float4* in = (const float4*)x;
  float4 a = in[2 * i];
  float4 b = in[2 * i + 1];
  uint4 o;
  o.x = (unsigned)f2bf(a.x) | ((unsigned)f2bf(a.y) << 16);
  o.y = (unsigned)f2bf(a.z) | ((unsigned)f2bf(a.w) << 16);
  o.z = (unsigned)f2bf(b.x) | ((unsigned)f2bf(b.y) << 16);
  o.w = (unsigned)f2bf(b.z) | ((unsigned)f2bf(b.w) << 16);
  ((uint4*)xb)[i] = o;
}

// ---------------------------------------------------------------------------
// Phase 1b: w [g][k][n] fp32 -> wt [g][n][k] bf16.  64x64 tiles via LDS (+1 pad).
__global__ __launch_bounds__(256) void cvt_wT_kernel(const float* __restrict__ w,
                                                     unsigned short* __restrict__ wt) {
  __shared__ unsigned short tile[64][65];
  const size_t base = (size_t)blockIdx.z * K_DIM * N_DIM;
  const int n0 = blockIdx.x * 64;
  const int k0 = blockIdx.y * 64;
  const int tx = threadIdx.x & 15;   // n chunk (4 floats)
  const int ty = threadIdx.x >> 4;   // k row
#pragma unroll
  for (int i = 0; i < 4; ++i) {
    int k = ty + i * 16;
    float4 v = *(const float4*)&w[base + (size_t)(k0 + k) * N_DIM + n0 + tx * 4];
    tile[k][tx * 4 + 0] = f2bf(v.x);
    tile[k][tx * 4 + 1] = f2bf(v.y);
    tile[k][tx * 4 + 2] = f2bf(v.z);
    tile[k][tx * 4 + 3] = f2bf(v.w);
  }
  __syncthreads();
  const int kx = threadIdx.x & 7;    // k chunk (8 elems -> 16B store)
  const int ny = threadIdx.x >> 3;   // n row
#pragma unroll
  for (int i = 0; i < 2; ++i) {
    int n = ny + i * 32;
    uint4 o;
    o.x = (unsigned)tile[kx * 8 + 0][n] | ((unsigned)tile[kx * 8 + 1][n] << 16);
    o.y = (unsigned)tile[kx * 8 + 2][n] | ((unsigned)tile[kx * 8 + 3][n] << 16);
    o.z = (unsigned)tile[kx * 8 + 4][n] | ((unsigned)tile[kx * 8 + 5][n] << 16);
    o.w = (unsigned)tile[kx * 8 + 6][n] | ((unsigned)tile[kx * 8 + 7][n] << 16);
    *(uint4*)&wt[base + (size_t)(n0 + n) * K_DIM + k0 + kx * 8] = o;
  }
}

// ---------------------------------------------------------------------------
// Phase 2 (fast): 256^2 8-phase bf16 GEMM.
//
// LDS map (ushort idx): half(b, mat, ks) = ((b*2+mat)*2+ks)*8192, each half =
// [256 rows][32 k] with 16B-slot swizzle  phys_slot = log_chunk ^ ((row>>1)&3).
// Staging is linear global_load_lds; the swizzle is applied to the GLOBAL
// source address (rule #21) and to the ds_read address — same involution.
//
// Phase schedule per K-tile t (buf b = t&1), 4 phases:
//  P1: ds(ks0, mi 0-3)+B      stage A.k1(t+1)->buf b^1
//  P2: ds(ks0, mi 4-7)        stage B.k1(t+1)->buf b^1
//  P3: ds(ks1, mi 0-3)+B      stage A.k0(t+2)->buf b      [k0 of b freed at P2]
//  P4: ds(ks1, mi 4-7)        stage B.k0(t+2)->buf b      vmcnt(4) checkpoint
// Checkpoint retires everything except the 2 newest half-tiles -> tile t+1
// fully resident entering P1(t+1); 2-3 half-tiles always in flight (never 0).

#define STAGE2(gp, matofs, B_, KS_, T_) do {                                   \
    const unsigned short* _g = (gp) + (size_t)(T_) * 64 + (KS_) * 32;          \
    unsigned short* _l = &lds[(((B_) * 4 + (matofs) + (KS_)) * 8192) + ldw];   \
    GLOAD_LDS16(_g, _l);                                                       \
    GLOAD_LDS16(_g + (size_t)128 * K_DIM, _l + 4096);                          \
  } while (0)

#define PHASE8(B_, KS_, QH_, LOADB_, STAGE_STMT, VM_STMT) do {                 \
    const int _ab = ((B_) * 4 + (KS_)) * 8192;                                 \
    const int _bb = ((B_) * 4 + 2 + (KS_)) * 8192;                             \
    _Pragma("unroll") for (int _i = 0; _i < 4; ++_i)                           \
      af[_i] = *(const bf16x8*)&lds[_ab + (wm + (QH_) * 64 + _i * 16 + fr) * 32 + pc8]; \
    if (LOADB_) {                                                              \
      _Pragma("unroll") for (int _i = 0; _i < 4; ++_i)                         \
        bfr[_i] = *(const bf16x8*)&lds[_bb + (wn + _i * 16 + fr) * 32 + pc8];  \
    }                                                                          \
    STAGE_STMT;                                                                \
    __builtin_amdgcn_s_barrier();                                              \
    asm volatile("s_waitcnt lgkmcnt(0)" ::: "memory");                         \
    __builtin_amdgcn_sched_barrier(0);                                         \
    __builtin_amdgcn_s_setprio(1);                                             \
    _Pragma("unroll") for (int _i = 0; _i < 4; ++_i)                           \
      _Pragma("unroll") for (int _j = 0; _j < 4; ++_j)                         \
        acc[(QH_) * 4 + _i][_j] = __builtin_amdgcn_mfma_f32_16x16x32_bf16(     \
            af[_i], bfr[_j], acc[(QH_) * 4 + _i][_j], 0, 0, 0);                \
    __builtin_amdgcn_s_setprio(0);                                             \
    VM_STMT;                                                                   \
    __builtin_amdgcn_s_barrier();                                              \
  } while (0)

__global__ __launch_bounds__(512, 2) void gemm_bt256_kernel(
    const unsigned short* __restrict__ A, const unsigned short* __restrict__ BT,
    float* __restrict__ C) {
  __shared__ unsigned short lds[65536];  // 128 KiB

  // T1: XCD-contiguous swizzle. nwg=1024 (%8==0 -> bijective). XCD x owns
  // M-tile rows [x*8, x*8+8) = exactly group x; row-major within XCD reuses
  // the 2MB A-panel in L2.
  const int id = blockIdx.x;                    // 0..1023
  const int swz = (id & 7) * 128 + (id >> 3);
  const int tm0 = (swz >> 4) * 256;
  const int tn0 = (swz & 15) * 256;
  const int g = swz >> 7;                       // group = m-tile-row / 8
  const unsigned short* Bg = BT + (size_t)g * ((size_t)K_DIM * N_DIM);

  const int tid = threadIdx.x;
  const int lane = tid & 63;
  const int wave = tid >> 6;
  const int wm = (wave >> 2) * 128;             // 2 wave-rows
  const int wn = (wave & 3) * 64;               // 4 wave-cols
  const int fr = lane & 15;                     // fragment row
  const int pc8 = ((lane >> 4) ^ ((fr >> 1) & 3)) * 8;  // swizzled k-chunk (T2)

  // staging source (global address carries the inverse swizzle)
  const int srow = tid >> 2;                                    // 0..127
  const int schunk = ((tid & 3) ^ ((tid >> 3) & 3)) * 8;        // swizzled src
  const unsigned short* pA = A + (size_t)(tm0 + srow) * K_DIM + schunk;
  const unsigned short* pB = Bg + (size_t)(tn0 + srow) * K_DIM + schunk;
  const int ldw = wave * 512;  // wave-uniform LDS dest (ushorts; HW adds lane*16B)

  f32x4 acc[8][4];
#pragma unroll
  for (int i = 0; i < 8; ++i)
#pragma unroll
    for (int j = 0; j < 4; ++j) acc[i][j] = (f32x4){0.f, 0.f, 0.f, 0.f};
  bf16x8 af[4], bfr[4];

  // Prologue: tile0 (4 halves) + tile1 k0 -> 12 loads; retire oldest 8 (tile0).
  STAGE2(pA, 0, 0, 0, 0);
  STAGE2(pB, 2, 0, 0, 0);
  STAGE2(pA, 0, 0, 1, 0);
  STAGE2(pB, 2, 0, 1, 0);
  STAGE2(pA, 0, 1, 0, 1);
  STAGE2(pB, 2, 1, 0, 1);
  asm volatile("s_waitcnt vmcnt(4)" ::: "memory");
  __builtin_amdgcn_s_barrier();

  for (int t = 0; t < 64; t += 2) {
    // ---- tile t (even, buf 0)
    PHASE8(0, 0, 0, 1, { STAGE2(pA, 0, 1, 1, t + 1); }, {});
    PHASE8(0, 0, 1, 0, { STAGE2(pB, 2, 1, 1, t + 1); }, {});
    PHASE8(0, 1, 0, 1, { if (t < 62) STAGE2(pA, 0, 0, 0, t + 2); }, {});
    PHASE8(0, 1, 1, 0, { if (t < 62) STAGE2(pB, 2, 0, 0, t + 2); },
           { if (t < 62) asm volatile("s_waitcnt vmcnt(4)" ::: "memory");
             else        asm volatile("s_waitcnt vmcnt(0)" ::: "memory"); });
    // ---- tile t+1 (odd, buf 1)
    PHASE8(1, 0, 0, 1, { if (t < 62) STAGE2(pA, 0, 0, 1, t + 2); }, {});
    PHASE8(1, 0, 1, 0, { if (t < 62) STAGE2(pB, 2, 0, 1, t + 2); }, {});
    PHASE8(1, 1, 0, 1, { if (t < 62) STAGE2(pA, 0, 1, 0, t + 3); }, {});
    PHASE8(1, 1, 1, 0, { if (t < 62) STAGE2(pB, 2, 1, 0, t + 3); },
           { if (t < 62) asm volatile("s_waitcnt vmcnt(4)" ::: "memory"); });
  }

  // Epilogue: C/D layout col = lane&15, row = (lane>>4)*4 + reg
  const int rr = (lane >> 4) * 4;
  const int cc = lane & 15;
#pragma unroll
  for (int mi = 0; mi < 8; ++mi)
#pragma unroll
    for (int ni = 0; ni < 4; ++ni) {
      size_t row = (size_t)(tm0 + wm + mi * 16 + rr);
      size_t col = (size_t)(tn0 + wn + ni * 16 + cc);
#pragma unroll
      for (int r = 0; r < 4; ++r) C[(row + r) * N_DIM + col] = acc[mi][ni][r];
    }
}

// ---------------------------------------------------------------------------
// Fallback helpers: 4x4 grid of 16x16x32 per wave (64x64 wave tile)
__device__ __forceinline__ void mfma_tile(const unsigned short* sA, const unsigned short* sB,
                                          f32x4 acc[4][4], int wm, int wn, int fr, int fk) {
  bf16x8 af[4], bb[4];
#pragma unroll
  for (int t = 0; t < 4; ++t) {
    af[t] = *(const bf16x8*)&sA[(wm + t * 16 + fr) * 32 + fk];
    bb[t] = *(const bf16x8*)&sB[(wn + t * 16 + fr) * 32 + fk];
  }
#pragma unroll
  for (int i = 0; i < 4; ++i)
#pragma unroll
    for (int j = 0; j < 4; ++j)
      acc[i][j] = __builtin_amdgcn_mfma_f32_16x16x32_bf16(af[i], bb[j], acc[i][j], 0, 0, 0);
}

__device__ __forceinline__ void epilogue(float* __restrict__ C, f32x4 acc[4][4],
                                         int tm0, int tn0, int wm, int wn, int lane) {
  const int rr = (lane >> 4) * 4;
  const int cc = lane & 15;
#pragma unroll
  for (int i = 0; i < 4; ++i)
#pragma unroll
    for (int j = 0; j < 4; ++j) {
      size_t row = (size_t)(tm0 + wm + i * 16 + rr);
      size_t col = (size_t)(tn0 + wn + j * 16 + cc);
#pragma unroll
      for (int r = 0; r < 4; ++r) C[(row + r) * N_DIM + col] = acc[i][j][r];
    }
}

// Fallback: zero-workspace fused-conversion GEMM (fp32 loads -> bf16 -> ds_write)
__global__ __launch_bounds__(256) void gemm_fused_kernel(const float* __restrict__ X,
                                                         const float* __restrict__ W,
                                                         float* __restrict__ C) {
  __shared__ unsigned short sA[128 * 32];
  __shared__ unsigned short sB[128 * 32];
  const int tn0 = blockIdx.x * 128;
  const int tm0 = blockIdx.y * 128;
  const int g = blockIdx.y >> 4;
  const float* Wg = W + (size_t)g * K_DIM * N_DIM;
  const int tid = threadIdx.x;
  const int lane = tid & 63, wave = tid >> 6;
  const int wm = (wave >> 1) * 64, wn = (wave & 1) * 64;
  const int fr = lane & 15, fk = (lane >> 4) * 8;

  const int ac = (tid & 7) * 4;   // A col (4 floats)
  const int ar = tid >> 3;        // A row base 0..31
  const int bn = (tid & 31) * 4;  // B n (4 floats)
  const int bk = tid >> 5;        // B k base 0..7

  f32x4 acc[4][4];
#pragma unroll
  for (int i = 0; i < 4; ++i)
#pragma unroll
    for (int j = 0; j < 4; ++j) acc[i][j] = (f32x4){0.f, 0.f, 0.f, 0.f};

  for (int k0 = 0; k0 < K_DIM; k0 += 32) {
    float4 av[4], bv[4];
#pragma unroll
    for (int p = 0; p < 4; ++p)
      av[p] = *(const float4*)&X[(size_t)(tm0 + ar + p * 32) * K_DIM + k0 + ac];
#pragma unroll
    for (int p = 0; p < 4; ++p)
      bv[p] = *(const float4*)&Wg[(size_t)(k0 + bk + p * 8) * N_DIM + tn0 + bn];
#pragma unroll
    for (int p = 0; p < 4; ++p) {
      ushort4 s;
      s.x = f2bf(av[p].x); s.y = f2bf(av[p].y); s.z = f2bf(av[p].z); s.w = f2bf(av[p].w);
      *(ushort4*)&sA[(ar + p * 32) * 32 + ac] = s;
    }
#pragma unroll
    for (int p = 0; p < 4; ++p) {  // transposed B write: sB[n][k]
      sB[(bn + 0) * 32 + bk + p * 8] = f2bf(bv[p].x);
      sB[(bn + 1) * 32 + bk + p * 8] = f2bf(bv[p].y);
      sB[(bn + 2) * 32 + bk + p * 8] = f2bf(bv[p].z);
      sB[(bn + 3) * 32 + bk + p * 8] = f2bf(bv[p].w);
    }
    __syncthreads();
    mfma_tile(sA, sB, acc, wm, wn, fr, fk);
    __syncthreads();
  }
  epilogue(C, acc, tm0, tn0, wm, wn, lane);
}

// ---------------------------------------------------------------------------
extern "C" void kernel_launch(void* const* d_in, const int* in_sizes, int n_in,
                              void* d_out, int out_size, void* d_ws, size_t ws_size,
                              hipStream_t stream) {
  const float* x = (const float*)d_in[0];
  const float* w = (const float*)d_in[1];
  float* out = (float*)d_out;
  const size_t xe = (size_t)M_TOT * K_DIM;            // 67,108,864
  const size_t we = (size_t)GROUPS * K_DIM * N_DIM;   // 134,217,728
  const size_t need = (xe + we) * sizeof(unsigned short);  // 402.7 MB

  if (ws_size >= need) {
    unsigned short* xb = (unsigned short*)d_ws;
    unsigned short* wt = xb + xe;
    cvt_x_kernel<<<dim3((unsigned)(xe / (256 * 8))), 256, 0, stream>>>(x, xb);
    cvt_wT_kernel<<<dim3(N_DIM / 64, K_DIM / 64, GROUPS), 256, 0, stream>>>(w, wt);
    gemm_bt256_kernel<<<dim3(16 * (M_TOT / 256)), dim3(512), 0, stream>>>(xb, wt, out);
  } else {
    gemm_fused_kernel<<<dim3(N_DIM / 128, M_TOT / 128), 256, 0, stream>>>(x, w, out);
  }
}